// Round 3
// baseline (231.338 us; speedup 1.0000x reference)
//
#include <hip/hip_runtime.h>
#include <hip/hip_cooperative_groups.h>
#include <math.h>

namespace cg = cooperative_groups;

// Problem constants: inputs (128, 64, 64, 32) fp32
#define BB 128
#define NN 64
#define DD 2048            // 64*32
#define ROWS (BB * NN)     // 8192
#define NBLK 1024          // cooperative grid: 4 blocks/CU * 256 CUs
#define NTHR 256

__device__ __forceinline__ float wave_reduce_sum(float v) {
    #pragma unroll
    for (int off = 32; off > 0; off >>= 1)
        v += __shfl_down(v, off, 64);
    return v;
}

// ---------------- Fused cooperative kernel ----------------
__global__ __launch_bounds__(NTHR, 4) void fused_loss_kernel(
        const float* __restrict__ x,
        float* __restrict__ inv_r,
        double* __restrict__ partials,
        float* __restrict__ out) {
    const int t = threadIdx.x;
    const int lane = t & 63, wid = t >> 6;

    __shared__ float red_d[4];   // per-wave diag partials (phase 1)
    __shared__ float invs[NN];   // phase 2 row scales
    __shared__ float vbuf[NTHR]; // phase 2 half-n combine
    __shared__ float red_s[2];   // phase 2 wave partials
    __shared__ double sd[NTHR];  // phase 3

    // ---- Phase 1: 8 rows per block (2 per wave) -> inv_r, diag partial ----
    {
        float diag = 0.f;
        #pragma unroll
        for (int rr = 0; rr < 2; ++rr) {
            const int row = blockIdx.x * 8 + wid * 2 + rr;
            const float4* p = reinterpret_cast<const float4*>(x + (size_t)row * DD);
            float s = 0.f;
            #pragma unroll
            for (int j = 0; j < 8; ++j) {              // 512 float4 per row
                float4 a = p[lane + 64 * j];
                s += a.x * a.x + a.y * a.y + a.z * a.z + a.w * a.w;
            }
            s = wave_reduce_sum(s);
            if (lane == 0) {
                float r = fmaxf(sqrtf(s), 1e-12f);
                float inv = 1.0f / r;
                inv_r[row] = inv;
                diag += s * inv * inv;                 // ||att_row||^2
            }
        }
        if (lane == 0) red_d[wid] = diag;
    }
    cg::this_grid().sync();

    // ---- Phase 2: 2 (batch, 128-col chunk) units per block ----
    {
        double part = 0.0;
        #pragma unroll
        for (int i = 0; i < 2; ++i) {
            const int u = blockIdx.x * 2 + i;          // 2048 units total
            const int b = u >> 4;                      // 128 batches
            const int c = u & 15;                      // 16 chunks of 128 cols
            __syncthreads();                           // protect invs/vbuf reuse
            if (t < NN) invs[t] = inv_r[b * NN + t];
            __syncthreads();

            const int t2 = t & 127;                    // column within chunk
            const int h = t >> 7;                      // n-half
            const float* xb = x + (size_t)b * NN * DD + c * 128 + t2;
            float v = 0.f;
            #pragma unroll
            for (int k = 0; k < 32; ++k) {
                const int n = h * 32 + k;
                v = fmaf(xb[(size_t)n * DD], invs[n], v);
            }
            vbuf[t] = v;
            __syncthreads();

            float pp = 0.f;
            if (t < 128) {
                const float vv = vbuf[t] + vbuf[t + 128];
                pp = vv * vv;
            }
            pp = wave_reduce_sum(pp);
            if (lane == 0 && wid < 2) red_s[wid] = pp;
            __syncthreads();
            if (t == 0) part += (double)(red_s[0] + red_s[1]);
        }
        if (t == 0) {
            const float dp = red_d[0] + red_d[1] + red_d[2] + red_d[3];
            partials[blockIdx.x] = part - (double)dp;
        }
    }
    cg::this_grid().sync();

    // ---- Phase 3: block 0 reduces 1024 double partials ----
    if (blockIdx.x == 0) {
        double a = 0.0;
        for (int i = t; i < NBLK; i += NTHR) a += partials[i];
        sd[t] = a;
        __syncthreads();
        #pragma unroll
        for (int off = 128; off > 0; off >>= 1) {
            if (t < off) sd[t] += sd[t + off];
            __syncthreads();
        }
        if (t == 0) out[0] = (float)(sd[0] / (double)BB);
    }
}

// ---------------- Fallback path (proven in Round 1) ----------------
#define NCHUNK 4
#define NBLK2 (BB * NCHUNK)

__global__ __launch_bounds__(256) void row_norm_kernel(
        const float* __restrict__ x,
        float* __restrict__ inv_r,
        float* __restrict__ d_term) {
    const int row = blockIdx.x;
    const int t = threadIdx.x;
    const float4* p = reinterpret_cast<const float4*>(x + (size_t)row * DD);
    float4 a = p[t];
    float4 b = p[t + 256];
    float s = a.x * a.x + a.y * a.y + a.z * a.z + a.w * a.w
            + b.x * b.x + b.y * b.y + b.z * b.z + b.w * b.w;
    s = wave_reduce_sum(s);
    __shared__ float red[4];
    const int lane = t & 63, wid = t >> 6;
    if (lane == 0) red[wid] = s;
    __syncthreads();
    if (t == 0) {
        float ss = red[0] + red[1] + red[2] + red[3];
        float r = fmaxf(sqrtf(ss), 1e-12f);
        float inv = 1.0f / r;
        inv_r[row] = inv;
        d_term[row] = ss * inv * inv;
    }
}

__global__ __launch_bounds__(256) void colsum_kernel(
        const float* __restrict__ x,
        const float* __restrict__ inv_r,
        float* __restrict__ s_partial) {
    const int b = blockIdx.x >> 2;
    const int c = blockIdx.x & (NCHUNK - 1);
    const int t = threadIdx.x;
    const int d0 = c * (DD / NCHUNK) + t * 2;

    __shared__ float invs[NN];
    if (t < NN) invs[t] = inv_r[b * NN + t];
    __syncthreads();

    const float2* x2 = reinterpret_cast<const float2*>(x);
    const size_t base = ((size_t)b * NN * DD + d0) >> 1;
    float vx = 0.f, vy = 0.f;
    #pragma unroll
    for (int n = 0; n < NN; ++n) {
        float2 a = x2[base + (size_t)n * (DD / 2)];
        vx = fmaf(a.x, invs[n], vx);
        vy = fmaf(a.y, invs[n], vy);
    }
    float p = vx * vx + vy * vy;
    p = wave_reduce_sum(p);
    __shared__ float red[4];
    const int lane = t & 63, wid = t >> 6;
    if (lane == 0) red[wid] = p;
    __syncthreads();
    if (t == 0)
        s_partial[blockIdx.x] = red[0] + red[1] + red[2] + red[3];
}

__global__ __launch_bounds__(256) void finalize_kernel(
        const float* __restrict__ d_term,
        const float* __restrict__ s_partial,
        float* __restrict__ out) {
    const int t = threadIdx.x;
    double acc_d = 0.0, acc_s = 0.0;
    for (int i = t; i < ROWS; i += 256) acc_d += (double)d_term[i];
    for (int i = t; i < NBLK2; i += 256) acc_s += (double)s_partial[i];
    __shared__ double sd[256];
    __shared__ double ss[256];
    sd[t] = acc_d;
    ss[t] = acc_s;
    __syncthreads();
    #pragma unroll
    for (int off = 128; off > 0; off >>= 1) {
        if (t < off) { sd[t] += sd[t + off]; ss[t] += ss[t + off]; }
        __syncthreads();
    }
    if (t == 0)
        out[0] = (float)((ss[0] - sd[0]) / (double)BB);
}

extern "C" void kernel_launch(void* const* d_in, const int* in_sizes, int n_in,
                              void* d_out, int out_size, void* d_ws, size_t ws_size,
                              hipStream_t stream) {
    const float* x = (const float*)d_in[0];
    float* out = (float*)d_out;

    float* inv_r = (float*)d_ws;                          // 8192 floats = 32 KB
    double* partials = (double*)((char*)d_ws + 32768);    // 1024 doubles = 8 KB
    float* d_term = (float*)((char*)d_ws + 65536);        // 8192 floats (fallback)
    float* s_part = d_term + ROWS;                        // 512 floats (fallback)

    void* args[] = {(void*)&x, (void*)&inv_r, (void*)&partials, (void*)&out};
    hipError_t e = hipLaunchCooperativeKernel((void*)fused_loss_kernel,
                                              dim3(NBLK), dim3(NTHR), args, 0, stream);
    if (e != hipSuccess) {
        // Fallback: proven 3-kernel path
        row_norm_kernel<<<ROWS, 256, 0, stream>>>(x, inv_r, d_term);
        colsum_kernel<<<NBLK2, 256, 0, stream>>>(x, inv_r, s_part);
        finalize_kernel<<<1, 256, 0, stream>>>(d_term, s_part, out);
    }
}

// Round 4
// 29.253 us; speedup vs baseline: 7.9083x; 7.9083x over previous
//
#include <hip/hip_runtime.h>
#include <math.h>

// Problem constants: inputs (128, 64, 64, 32) fp32
#define BB 128
#define NN 64
#define DD 2048            // 64*32
#define NTHR 1024          // 16 waves: one block handles one full batch (512 KB)

__device__ __forceinline__ float wave_reduce_sum(float v) {
    #pragma unroll
    for (int off = 32; off > 0; off >>= 1)
        v += __shfl_down(v, off, 64);
    return v;
}

// One block per batch. Phase A: row norms (per-wave). Phase B: column sums
// with LDS-held inv scales (re-read hits L2/L3). No cross-block deps.
__global__ __launch_bounds__(NTHR) void batch_loss_kernel(
        const float* __restrict__ x,
        double* __restrict__ partials) {
    const int b = blockIdx.x;
    const int t = threadIdx.x;
    const int lane = t & 63, wid = t >> 6;     // 16 waves

    __shared__ float invs[NN];
    __shared__ float diag_w[16];
    __shared__ float red[16];

    const float* xb = x + (size_t)b * NN * DD;

    // ---- Phase A: wave w -> rows 4w..4w+3: sumsq, inv norm, diag term ----
    float diag = 0.f;
    #pragma unroll
    for (int rr = 0; rr < 4; ++rr) {
        const int row = wid * 4 + rr;
        const float4* p = reinterpret_cast<const float4*>(xb + (size_t)row * DD);
        float s = 0.f;
        #pragma unroll
        for (int j = 0; j < 8; ++j) {          // 512 float4 per row
            float4 a = p[lane + 64 * j];
            s += a.x * a.x + a.y * a.y + a.z * a.z + a.w * a.w;
        }
        s = wave_reduce_sum(s);
        if (lane == 0) {
            float r = fmaxf(sqrtf(s), 1e-12f);
            float inv = 1.0f / r;
            invs[row] = inv;
            diag += s * inv * inv;             // ||att_row||^2 (== 1 normally)
        }
    }
    if (lane == 0) diag_w[wid] = diag;
    __syncthreads();

    // ---- Phase B: thread t owns columns 2t, 2t+1; v = sum_n x[n][d]*inv[n] ----
    const float2* x2 = reinterpret_cast<const float2*>(xb);
    float vx0 = 0.f, vy0 = 0.f, vx1 = 0.f, vy1 = 0.f;   // 2 chains for ILP
    #pragma unroll 8
    for (int n = 0; n < NN; n += 2) {
        float2 a0 = x2[(size_t)n * (DD / 2) + t];
        float2 a1 = x2[(size_t)(n + 1) * (DD / 2) + t];
        float i0 = invs[n], i1 = invs[n + 1];
        vx0 = fmaf(a0.x, i0, vx0);
        vy0 = fmaf(a0.y, i0, vy0);
        vx1 = fmaf(a1.x, i1, vx1);
        vy1 = fmaf(a1.y, i1, vy1);
    }
    const float vx = vx0 + vx1, vy = vy0 + vy1;
    float p = vx * vx + vy * vy;
    p = wave_reduce_sum(p);
    if (lane == 0) red[wid] = p;
    __syncthreads();

    if (t == 0) {
        double sp = 0.0, dp = 0.0;
        #pragma unroll
        for (int w = 0; w < 16; ++w) { sp += (double)red[w]; dp += (double)diag_w[w]; }
        partials[b] = sp - dp;                 // ||v_b||^2 - sum_n ||att_n||^2
    }
}

// Final: mean over batches (fixed-order double sum -> deterministic).
__global__ __launch_bounds__(128) void finalize_kernel(
        const double* __restrict__ partials,
        float* __restrict__ out) {
    const int t = threadIdx.x;
    __shared__ double sd[128];
    sd[t] = partials[t];
    __syncthreads();
    #pragma unroll
    for (int off = 64; off > 0; off >>= 1) {
        if (t < off) sd[t] += sd[t + off];
        __syncthreads();
    }
    if (t == 0) out[0] = (float)(sd[0] / (double)BB);
}

extern "C" void kernel_launch(void* const* d_in, const int* in_sizes, int n_in,
                              void* d_out, int out_size, void* d_ws, size_t ws_size,
                              hipStream_t stream) {
    const float* x = (const float*)d_in[0];
    float* out = (float*)d_out;
    double* partials = (double*)d_ws;          // 128 doubles

    batch_loss_kernel<<<BB, NTHR, 0, stream>>>(x, partials);
    finalize_kernel<<<1, 128, 0, stream>>>(partials, out);
}